// Round 4
// baseline (220.805 us; speedup 1.0000x reference)
//
#include <hip/hip_runtime.h>
#include <math.h>

#define NROWS 131072
#define DIM   64
#define KCENT 1024
#define DECAY 0.99f
#define EPS_  1e-5f

typedef unsigned int u32;
typedef unsigned short u16;
typedef __attribute__((ext_vector_type(8))) short short8b;
typedef __attribute__((ext_vector_type(16))) float floatx16;

// ---------------- ws layout (float elements) ----------------
// csum    [K*D]    @ 0        (zeroed by k_ctrans)
// cnt     [K]      @ 65536    (int, zeroed by k_ctrans)
// cs      [K]      @ 66560
// cnewT   [K*D]    @ 67584
// ind     [N]      @ 133120   (int)
// pk      [N]      @ 264192   (int2: {row, cluster} in sorted order)
// start   [K]      @ 526336   (int)
// cursor16[K*16]   @ 527360   (int, 64B-spread atomic cursors)
// centB   [K*68]   @ 543744   (u32: bf16 hi 32dw | lo 32dw | csq@64 | pad; 272B rows)

__device__ inline u16 bf16rne(float f) {
    u32 u = __float_as_uint(f);
    return (u16)((u + 0x7FFFu + ((u >> 16) & 1u)) >> 16);
}

// ---------- K1: centroid transpose/split + zero csum/cnt ----------
__global__ void k_ctrans(const float* __restrict__ cent, u32* __restrict__ centB,
                         float* __restrict__ zero_base) {
    int tid = blockIdx.x * 256 + threadIdx.x;   // 0..1023
    // zero csum+cnt (66560 floats = 16640 float4)
    float4 z = make_float4(0.f, 0.f, 0.f, 0.f);
    for (int i = tid; i < 16640; i += 1024) ((float4*)zero_base)[i] = z;

    int k = tid;
    u32* row = centB + (size_t)k * 68;
    float csq = 0.f;
#pragma unroll
    for (int d0 = 0; d0 < 32; ++d0) {
        float f0 = cent[(2 * d0) * KCENT + k];      // coalesced across lanes
        float f1 = cent[(2 * d0 + 1) * KCENT + k];
        u16 h0 = bf16rne(f0), h1 = bf16rne(f1);
        u16 s0 = bf16rne(f0 - __uint_as_float((u32)h0 << 16));
        u16 s1 = bf16rne(f1 - __uint_as_float((u32)h1 << 16));
        csq = fmaf(f0, f0, fmaf(f1, f1, csq));
        row[d0]      = (u32)h0 | ((u32)h1 << 16);   // hi
        row[32 + d0] = (u32)s0 | ((u32)s1 << 16);   // lo
    }
    row[64] = __float_as_uint(csq);
}

// ---------- K2: MFMA assignment ----------
// dot ~= xh.ch + xh.cl + xl.ch  (lo*lo dropped: ~2^-18 rel, below split residual)
// C layout (m74/m101): col=lane&31, row=(reg&3)+8*(reg>>2)+4*(lane>>5).
// v5 vs v2(62us)/v4(72us): occupancy-dominated regime confirmed (16 waves/CU=62,
// 8 waves/CU=72 at same-or-half pipe demand). Keep v2's 32-rows/wave structure;
// repartition into 4-wave blocks, grid 1024 -> 4 blocks/CU (LDS 38912*4=152KB
// fits exactly). Same 16 waves/CU, but 4 INDEPENDENT barrier groups: while one
// block drains its staging barrier, 3 others issue MFMA/LDS (m114 implicit
// overlap). setprio(1) around MFMA: desynced blocks give the CU scheduler
// roles to arbitrate (T5 regime).
__global__ __launch_bounds__(256, 4) void k_assign(
    const float* __restrict__ x, const u32* __restrict__ centB,
    int* __restrict__ ind, int* __restrict__ cnt) {
    __shared__ __align__(16) char buf[2][17408];   // 64 cents x 272B, double-buffered
    __shared__ int hist[KCENT];
    const int tid  = threadIdx.x;                  // 0..255
    const int lane = tid & 63;
    const int wid  = tid >> 6;                     // 0..3
    const int half = lane >> 5;
    const int nl   = lane & 31;

    const int rowbase = blockIdx.x * 128 + wid * 32;

    // A-frags: 4 hi + 4 lo for this wave's 32 rows (dims t4*16+half*8 .. +8)
    short8b ah[4], al[4];
    {
        const float* xr = x + (size_t)(rowbase + nl) * DIM;
#pragma unroll
        for (int t4 = 0; t4 < 4; ++t4) {
            int d0 = t4 * 16 + half * 8;
            float4 f0 = *(const float4*)(xr + d0);
            float4 f1 = *(const float4*)(xr + d0 + 4);
            float fv[8] = {f0.x, f0.y, f0.z, f0.w, f1.x, f1.y, f1.z, f1.w};
            short8b va, vb;
#pragma unroll
            for (int j = 0; j < 8; ++j) {
                u16 h = bf16rne(fv[j]);
                float lo = fv[j] - __uint_as_float((u32)h << 16);
                va[j] = (short)h;
                vb[j] = (short)bf16rne(lo);
            }
            ah[t4] = va;
            al[t4] = vb;
        }
    }

    hist[tid] = 0; hist[tid + 256] = 0; hist[tid + 512] = 0; hist[tid + 768] = 0;

    float best[16];
#pragma unroll
    for (int r = 0; r < 16; ++r) best[r] = __uint_as_float(0xFF800000u); // -inf

    // staging: tile kt = 17408B = 17 granule-blocks of 1KB; block b -> wave (b%4)
    const char* gbase = (const char*)centB;
#define STAGE(KT, DST)                                                              \
    {                                                                               \
        const char* _src = gbase + (size_t)(KT) * 17408;                            \
        for (int b = wid; b < 17; b += 4) {                                         \
            __builtin_amdgcn_global_load_lds(                                       \
                (const __attribute__((address_space(1))) u32*)(_src + b * 1024 +    \
                                                               lane * 16),          \
                (__attribute__((address_space(3))) u32*)((DST) + b * 1024),         \
                16, 0, 0);                                                          \
        }                                                                           \
    }

    STAGE(0, buf[0]);
    __syncthreads();   // drains vmcnt(0): tile 0 landed

    for (int kt = 0; kt < 16; ++kt) {
        char* bc = buf[kt & 1];
        if (kt < 15) STAGE(kt + 1, buf[(kt + 1) & 1]);  // drained at closing barrier

#pragma unroll
        for (int sub = 0; sub < 2; ++sub) {
            const char* base = bc + (size_t)(sub * 32 + nl) * 272 + half * 16;
            short8b bh[4], bl[4];
#pragma unroll
            for (int t4 = 0; t4 < 4; ++t4) bh[t4] = *(const short8b*)(base + t4 * 32);
#pragma unroll
            for (int t4 = 0; t4 < 4; ++t4) bl[t4] = *(const short8b*)(base + 128 + t4 * 32);
            float cq = *(const float*)(bc + (size_t)(sub * 32 + nl) * 272 + 256);
            float mh = -0.5f * cq;

            floatx16 acc;
#pragma unroll
            for (int i = 0; i < 16; ++i) acc[i] = mh;
            __builtin_amdgcn_s_setprio(1);
#pragma unroll
            for (int t4 = 0; t4 < 4; ++t4)
                acc = __builtin_amdgcn_mfma_f32_32x32x16_bf16(ah[t4], bh[t4], acc, 0, 0, 0);
#pragma unroll
            for (int t4 = 0; t4 < 4; ++t4)
                acc = __builtin_amdgcn_mfma_f32_32x32x16_bf16(ah[t4], bl[t4], acc, 0, 0, 0);
#pragma unroll
            for (int t4 = 0; t4 < 4; ++t4)
                acc = __builtin_amdgcn_mfma_f32_32x32x16_bf16(al[t4], bh[t4], acc, 0, 0, 0);
            __builtin_amdgcn_s_setprio(0);

            const u32 tag = (u32)(kt * 2 + sub);     // 5 bits; cidx = tag*32 + nl
#pragma unroll
            for (int r = 0; r < 16; ++r) {
                u32 pkv = (__float_as_uint(acc[r]) & 0xFFFFFFE0u) | tag;
                best[r] = fmaxf(best[r], __uint_as_float(pkv));
            }
        }
        __syncthreads();   // tile kt+1 landed; buf[kt&1] reusable
    }
#undef STAGE

    // cross-lane argmax within each 32-lane half; unpack 5-bit tag + lane -> cidx
#pragma unroll
    for (int r = 0; r < 16; ++r) {
        float b0 = best[r];
        int   i0 = ((int)(__float_as_uint(b0) & 31u) << 5) | nl;
#pragma unroll
        for (int m = 1; m < 32; m <<= 1) {
            float bp = __shfl_xor(b0, m, 64);
            int   ip = __shfl_xor(i0, m, 64);
            if (bp > b0 || (bp == b0 && ip < i0)) { b0 = bp; i0 = ip; }
        }
        if (nl == 0) {
            int mrow = (r & 3) + 8 * (r >> 2) + 4 * half;
            ind[rowbase + mrow] = i0;
            atomicAdd(&hist[i0], 1);
        }
    }
    __syncthreads();
#pragma unroll
    for (int i = 0; i < 4; ++i) {
        int bkt = tid + i * 256;
        int v = hist[bkt];
        if (v) atomicAdd(&cnt[bkt], v);
    }
}

// ---------- K3: EMA stats + Laplace cs + prefix sum (shuffle-scan, 2 barriers) ----------
__global__ void k_scan(const float* __restrict__ cluster_size,
                       const int* __restrict__ cnt,
                       float* __restrict__ cs,
                       int* __restrict__ start, int* __restrict__ cursor16,
                       float* __restrict__ loss) {
    __shared__ float wsumf[16];
    __shared__ int   wtot[16];
    __shared__ int   woff[16];
    __shared__ float ftot_s;
    const int t = threadIdx.x;           // 0..1023
    const int lane = t & 63, w = t >> 6;
    const int c = cnt[t];
    float cls = DECAY * cluster_size[t] + (1.0f - DECAY) * (float)c;

    // wave reduce (float) + wave inclusive scan (int)
    float s = cls;
#pragma unroll
    for (int m = 1; m < 64; m <<= 1) s += __shfl_xor(s, m, 64);
    int inc = c;
#pragma unroll
    for (int m = 1; m < 64; m <<= 1) {
        int u = __shfl_up(inc, m, 64);
        if (lane >= m) inc += u;
    }
    if (lane == 0)  wsumf[w] = s;
    if (lane == 63) wtot[w]  = inc;
    __syncthreads();
    if (t == 0) {
        int run = 0; float ft = 0.f;
#pragma unroll
        for (int i = 0; i < 16; ++i) { woff[i] = run; run += wtot[i]; ft += wsumf[i]; }
        ftot_s = ft;
        loss[0] = 0.f;                 // fold loss-slot zeroing here
    }
    __syncthreads();
    float ntot = ftot_s;
    cs[t] = (cls + EPS_) / (ntot + KCENT * EPS_) * ntot;
    int excl = woff[w] + inc - c;
    start[t] = excl;
    cursor16[t * 16] = excl;
}

// ---------- K4: scatter with block-aggregated ranks ----------
// Longest per-address global atomic chain drops from max-cluster-size (~5K)
// to <= #blocks (512). LDS atomic old-value = intra-block rank.
__global__ __launch_bounds__(256) void k_scatter(
    const int* __restrict__ ind, int* __restrict__ cursor16,
    int2* __restrict__ pk) {
    __shared__ int lh[KCENT];
#pragma unroll
    for (int i = 0; i < KCENT / 256; ++i) lh[threadIdx.x + i * 256] = 0;
    __syncthreads();

    const int n  = blockIdx.x * 256 + threadIdx.x;
    const int bi = ind[n];
    const int rank = atomicAdd(&lh[bi], 1);   // LDS atomic: old = my rank
    __syncthreads();

#pragma unroll
    for (int i = 0; i < KCENT / 256; ++i) {
        int k = threadIdx.x + i * 256;
        int c = lh[k];
        int base = 0;
        if (c) base = atomicAdd(&cursor16[k * 16], c);  // one per distinct cluster
        lh[k] = base;
    }
    __syncthreads();

    pk[lh[bi] + rank] = make_int2(n, bi);
}

// ---------- K5: segment sum over uniform 32-row wave-windows ----------
__global__ __launch_bounds__(256) void k_segsum(
    const float* __restrict__ x, const int2* __restrict__ pk,
    float* __restrict__ csum) {
    const int wgid = blockIdx.x * 4 + (threadIdx.x >> 6);  // 0..4095
    const int lane = threadIdx.x & 63;
    const int r0   = wgid * 32;

    float acc = 0.f;
    int cur = pk[r0].y;
#pragma unroll 4
    for (int r = r0; r < r0 + 32; r += 2) {
        int2 a = pk[r];                   // wave-uniform -> scalar 8B load
        int2 b = pk[r + 1];
        float v0 = x[(size_t)a.x * DIM + lane];   // coalesced 256B/row
        float v1 = x[(size_t)b.x * DIM + lane];
        if (a.y != cur) {                 // wave-uniform branch, rare
            atomicAdd(&csum[(size_t)cur * DIM + lane], acc);
            acc = 0.f; cur = a.y;
        }
        acc += v0;
        if (b.y != cur) {
            atomicAdd(&csum[(size_t)cur * DIM + lane], acc);
            acc = 0.f; cur = b.y;
        }
        acc += v1;
    }
    atomicAdd(&csum[(size_t)cur * DIM + lane], acc);
}

// ---------- K6: centroids_new, stored transposed [K][D] ----------
__global__ void k_newcent(const float* __restrict__ avg,
                          const float* __restrict__ csum,
                          const float* __restrict__ cs,
                          float* __restrict__ cnewT) {
    int idx = blockIdx.x * blockDim.x + threadIdx.x;  // = k*64 + d
    int k = idx >> 6, d = idx & 63;
    float v = DECAY * avg[d * KCENT + k] + (1.0f - DECAY) * csum[idx];
    cnewT[idx] = v / cs[k];
}

// ---------- K7: gather quantized rows + MSE loss ----------
__global__ __launch_bounds__(256) void k_out(
    const float* __restrict__ x, const int* __restrict__ ind,
    const float* __restrict__ cnewT, float* __restrict__ out,
    float* __restrict__ loss) {
    const int tid = threadIdx.x;
    const int l16 = tid & 15;
    float p = 0.f;

    for (int g = blockIdx.x; g < NROWS / 16; g += 2048) {
        int row = g * 16 + (tid >> 4);
        int k = ind[row];
        float4 q  = ((const float4*)(cnewT + (size_t)k * DIM))[l16];
        float4 xw = ((const float4*)(x + (size_t)row * DIM))[l16];
        ((float4*)(out + (size_t)row * DIM))[l16] = q;
        float dx = xw.x - q.x, dy = xw.y - q.y, dz = xw.z - q.z, dw = xw.w - q.w;
        p += dx * dx + dy * dy + dz * dz + dw * dw;
    }

    __shared__ float red[256];
    red[tid] = p;
    __syncthreads();
    for (int off = 128; off > 0; off >>= 1) {
        if (tid < off) red[tid] += red[tid + off];
        __syncthreads();
    }
    if (tid == 0)
        atomicAdd(loss, red[0] * (1.0f / ((float)NROWS * (float)DIM)));
}

extern "C" void kernel_launch(void* const* d_in, const int* in_sizes, int n_in,
                              void* d_out, int out_size, void* d_ws, size_t ws_size,
                              hipStream_t stream) {
    const float* x            = (const float*)d_in[0];
    const float* cent         = (const float*)d_in[1];
    const float* cluster_size = (const float*)d_in[2];
    const float* avg          = (const float*)d_in[3];
    float* out = (float*)d_out;

    float* ws       = (float*)d_ws;
    float* csum     = ws;                     // K*D
    int*   cnt      = (int*)(ws + 65536);     // K
    float* cs       = ws + 66560;             // K
    float* cnewT    = ws + 67584;             // K*D
    int*   ind      = (int*)(ws + 133120);    // N
    int2*  pk       = (int2*)(ws + 264192);   // N int2
    int*   start    = (int*)(ws + 526336);    // K
    int*   cursor16 = (int*)(ws + 527360);    // 16K
    u32*   centB    = (u32*)(ws + 543744);    // K*68
    float* loss     = out + (size_t)NROWS * DIM;

    k_ctrans <<<KCENT / 256, 256, 0, stream>>>(cent, centB, csum);
    k_assign <<<NROWS / 128, 256, 0, stream>>>(x, centB, ind, cnt);
    k_scan   <<<1, KCENT, 0, stream>>>(cluster_size, cnt, cs, start, cursor16, loss);
    k_scatter<<<NROWS / 256, 256, 0, stream>>>(ind, cursor16, pk);
    k_segsum <<<NROWS / 128, 256, 0, stream>>>(x, pk, csum);
    k_newcent<<<(KCENT * DIM) / 256, 256, 0, stream>>>(avg, csum, cs, cnewT);
    k_out    <<<2048, 256, 0, stream>>>(x, ind, cnewT, out, loss);
}

// Round 5
// 218.974 us; speedup vs baseline: 1.0084x; 1.0084x over previous
//
#include <hip/hip_runtime.h>
#include <math.h>

#define NROWS 131072
#define DIM   64
#define KCENT 1024
#define DECAY 0.99f
#define EPS_  1e-5f

typedef unsigned int u32;
typedef unsigned short u16;
typedef __attribute__((ext_vector_type(8))) short short8b;
typedef __attribute__((ext_vector_type(16))) float floatx16;

// ---------------- ws layout (float elements) ----------------
// csum    [K*D]    @ 0        (zeroed by k_ctrans)
// cnt     [K]      @ 65536    (int, zeroed by k_ctrans)
// cs      [K]      @ 66560
// cnewT   [K*D]    @ 67584
// ind     [N]      @ 133120   (int)
// pk      [N]      @ 264192   (int2)
// start   [K]      @ 526336   (int)
// cursor16[K*16]   @ 527360   (int)
// centB   [66560]  @ 543744   (u32, frag-major: 32 blocks of 32 cents;
//          per block s: 8 planes x 1KB (4 hi + 4 lo; plane = one wave-wide
//          coalesced dwordx4: lane l -> cent s*32+(l&31), dims t4*16+(l>>5)*8)
//          + csq[32] @ +8KB; block stride 8320B = 2080 u32)

__device__ inline u16 bf16rne(float f) {
    u32 u = __float_as_uint(f);
    return (u16)((u + 0x7FFFu + ((u >> 16) & 1u)) >> 16);
}

// ---------- K1: centroid transpose/split into frag-major planes ----------
__global__ void k_ctrans(const float* __restrict__ cent, u32* __restrict__ centB,
                         float* __restrict__ zero_base) {
    int tid = blockIdx.x * 256 + threadIdx.x;   // 0..1023
    // zero csum+cnt (66560 floats = 16640 float4)
    float4 z = make_float4(0.f, 0.f, 0.f, 0.f);
    for (int i = tid; i < 16640; i += 1024) ((float4*)zero_base)[i] = z;

    int k = tid;
    u32 base = (u32)(k >> 5) * 2080;            // 32-cent block, 8320B stride
    u32 c5   = (u32)(k & 31);
    float csq = 0.f;
#pragma unroll
    for (int w = 0; w < 32; ++w) {              // dim-pair w: dims 2w, 2w+1
        float f0 = cent[(2 * w) * KCENT + k];   // coalesced across lanes
        float f1 = cent[(2 * w + 1) * KCENT + k];
        u16 h0 = bf16rne(f0), h1 = bf16rne(f1);
        u16 s0 = bf16rne(f0 - __uint_as_float((u32)h0 << 16));
        u16 s1 = bf16rne(f1 - __uint_as_float((u32)h1 << 16));
        csq = fmaf(f0, f0, fmaf(f1, f1, csq));
        // frag-major: plane t4 = w>>3, frag-half = (w>>2)&1, word-in-frag = w&3
        u32 lane_p = c5 + 32u * ((w >> 2) & 1u);
        u32 off = (u32)(w >> 3) * 256u + lane_p * 4u + (u32)(w & 3);
        centB[base + off]         = (u32)h0 | ((u32)h1 << 16);   // hi planes 0..3
        centB[base + 1024u + off] = (u32)s0 | ((u32)s1 << 16);   // lo planes 4..7
    }
    centB[base + 2048u + c5] = __float_as_uint(csq);
}

// ---------- K2: MFMA assignment — barrier-free, B streamed from L2 ----------
// dot ~= xh.ch + xh.cl + xl.ch ; C layout (m74/m101): col=lane&31 (cent),
// row=(reg&3)+8*(reg>>2)+4*(lane>>5).
// v6 vs v2(62us)/v4(72us)/v5(76us): measured time ~= SUM of pipe demands
// (MFMA 20.7 + LDS-read 20.5 + VALU 12) because barrier-locked waves phase-
// align on one pipe at a time; all scheduling fixes were null. So DELETE the
// LDS pipe: frag-major centB lets each B-frag be one coalesced L2 dwordx4
// (L2 ~135B/cyc/CU covers it), register-double-buffered one sub ahead.
// 64 rows/wave amortizes B over 2 MFMA chains; zero __shared__ staging,
// zero main-loop barriers -> waves free-run, pipes overlap naturally.
__global__ __launch_bounds__(256, 2) void k_assign(
    const float* __restrict__ x, const u32* __restrict__ centB,
    int* __restrict__ ind, int* __restrict__ cnt) {
    __shared__ int hist[KCENT];
    const int tid  = threadIdx.x;                  // 0..255
    const int lane = tid & 63;
    const int wid  = tid >> 6;                     // 0..3
    const int half = lane >> 5;
    const int nl   = lane & 31;

    const int rowbase = blockIdx.x * 256 + wid * 64;

    hist[tid] = 0; hist[tid + 256] = 0; hist[tid + 512] = 0; hist[tid + 768] = 0;

    // A-frags: 2 row-groups x (4 hi + 4 lo) for this wave's 64 rows
    short8b ah[2][4], al[2][4];
#pragma unroll
    for (int rg = 0; rg < 2; ++rg) {
        const float* xr = x + (size_t)(rowbase + rg * 32 + nl) * DIM;
#pragma unroll
        for (int t4 = 0; t4 < 4; ++t4) {
            int d0 = t4 * 16 + half * 8;
            float4 f0 = *(const float4*)(xr + d0);
            float4 f1 = *(const float4*)(xr + d0 + 4);
            float fv[8] = {f0.x, f0.y, f0.z, f0.w, f1.x, f1.y, f1.z, f1.w};
            short8b va, vb;
#pragma unroll
            for (int j = 0; j < 8; ++j) {
                u16 h = bf16rne(fv[j]);
                float lo = fv[j] - __uint_as_float((u32)h << 16);
                va[j] = (short)h;
                vb[j] = (short)bf16rne(lo);
            }
            ah[rg][t4] = va;
            al[rg][t4] = vb;
        }
    }

    __syncthreads();   // hist zeroing complete before any epilogue atomics

    float best[2][16];
#pragma unroll
    for (int rg = 0; rg < 2; ++rg)
#pragma unroll
        for (int r = 0; r < 16; ++r) best[rg][r] = __uint_as_float(0xFF800000u);

    // B-frag load: one 32-cent block s (0..31), fully coalesced dwordx4 planes
#define LOADSUB(S, BH, BL, CQ) {                                         \
        const u32* sb = centB + (size_t)(S) * 2080;                      \
        BH[0] = *(const short8b*)(sb + 0 * 256 + lane * 4);              \
        BH[1] = *(const short8b*)(sb + 1 * 256 + lane * 4);              \
        BH[2] = *(const short8b*)(sb + 2 * 256 + lane * 4);              \
        BH[3] = *(const short8b*)(sb + 3 * 256 + lane * 4);              \
        BL[0] = *(const short8b*)(sb + 4 * 256 + lane * 4);              \
        BL[1] = *(const short8b*)(sb + 5 * 256 + lane * 4);              \
        BL[2] = *(const short8b*)(sb + 6 * 256 + lane * 4);              \
        BL[3] = *(const short8b*)(sb + 7 * 256 + lane * 4);              \
        CQ = __uint_as_float(sb[2048 + nl]);                             \
    }

#define PROCSUB(BH, BL, CQ, S) {                                                        \
        float mhv = -0.5f * CQ;                                                         \
        floatx16 a0, a1;                                                                \
        _Pragma("unroll") for (int i = 0; i < 16; ++i) { a0[i] = mhv; a1[i] = mhv; }    \
        _Pragma("unroll") for (int t4 = 0; t4 < 4; ++t4) {                              \
            a0 = __builtin_amdgcn_mfma_f32_32x32x16_bf16(ah[0][t4], BH[t4], a0, 0,0,0); \
            a1 = __builtin_amdgcn_mfma_f32_32x32x16_bf16(ah[1][t4], BH[t4], a1, 0,0,0); \
        }                                                                               \
        _Pragma("unroll") for (int t4 = 0; t4 < 4; ++t4) {                              \
            a0 = __builtin_amdgcn_mfma_f32_32x32x16_bf16(ah[0][t4], BL[t4], a0, 0,0,0); \
            a1 = __builtin_amdgcn_mfma_f32_32x32x16_bf16(ah[1][t4], BL[t4], a1, 0,0,0); \
        }                                                                               \
        _Pragma("unroll") for (int t4 = 0; t4 < 4; ++t4) {                              \
            a0 = __builtin_amdgcn_mfma_f32_32x32x16_bf16(al[0][t4], BH[t4], a0, 0,0,0); \
            a1 = __builtin_amdgcn_mfma_f32_32x32x16_bf16(al[1][t4], BH[t4], a1, 0,0,0); \
        }                                                                               \
        const u32 tg = (u32)(S);                                                        \
        _Pragma("unroll") for (int r = 0; r < 16; ++r) {                                \
            u32 p0 = (__float_as_uint(a0[r]) & 0xFFFFFFE0u) | tg;                       \
            best[0][r] = fmaxf(best[0][r], __uint_as_float(p0));                        \
            u32 p1 = (__float_as_uint(a1[r]) & 0xFFFFFFE0u) | tg;                       \
            best[1][r] = fmaxf(best[1][r], __uint_as_float(p1));                        \
        }                                                                               \
    }

    short8b h0[4], l0[4], h1[4], l1[4];
    float q0, q1;
    LOADSUB(0, h0, l0, q0);
    for (int s = 0; s < 32; s += 2) {          // reg double-buffer, 1 sub ahead
        LOADSUB(s + 1, h1, l1, q1);
        PROCSUB(h0, l0, q0, s);
        if (s < 30) LOADSUB(s + 2, h0, l0, q0);
        PROCSUB(h1, l1, q1, s + 1);
    }
#undef LOADSUB
#undef PROCSUB

    // cross-lane argmax within each 32-lane half; unpack 5-bit tag + lane
#pragma unroll
    for (int rg = 0; rg < 2; ++rg) {
#pragma unroll
        for (int r = 0; r < 16; ++r) {
            float b0 = best[rg][r];
            int   i0 = ((int)(__float_as_uint(b0) & 31u) << 5) | nl;
#pragma unroll
            for (int m = 1; m < 32; m <<= 1) {
                float bp = __shfl_xor(b0, m, 64);
                int   ip = __shfl_xor(i0, m, 64);
                if (bp > b0 || (bp == b0 && ip < i0)) { b0 = bp; i0 = ip; }
            }
            if (nl == 0) {
                int mrow = (r & 3) + 8 * (r >> 2) + 4 * half;
                ind[rowbase + rg * 32 + mrow] = i0;
                atomicAdd(&hist[i0], 1);
            }
        }
    }
    __syncthreads();
#pragma unroll
    for (int i = 0; i < 4; ++i) {
        int bkt = tid + i * 256;
        int v = hist[bkt];
        if (v) atomicAdd(&cnt[bkt], v);
    }
}

// ---------- K3: EMA stats + Laplace cs + prefix sum ----------
__global__ void k_scan(const float* __restrict__ cluster_size,
                       const int* __restrict__ cnt,
                       float* __restrict__ cs,
                       int* __restrict__ start, int* __restrict__ cursor16,
                       float* __restrict__ loss) {
    __shared__ float wsumf[16];
    __shared__ int   wtot[16];
    __shared__ int   woff[16];
    __shared__ float ftot_s;
    const int t = threadIdx.x;           // 0..1023
    const int lane = t & 63, w = t >> 6;
    const int c = cnt[t];
    float cls = DECAY * cluster_size[t] + (1.0f - DECAY) * (float)c;

    float s = cls;
#pragma unroll
    for (int m = 1; m < 64; m <<= 1) s += __shfl_xor(s, m, 64);
    int inc = c;
#pragma unroll
    for (int m = 1; m < 64; m <<= 1) {
        int u = __shfl_up(inc, m, 64);
        if (lane >= m) inc += u;
    }
    if (lane == 0)  wsumf[w] = s;
    if (lane == 63) wtot[w]  = inc;
    __syncthreads();
    if (t == 0) {
        int run = 0; float ft = 0.f;
#pragma unroll
        for (int i = 0; i < 16; ++i) { woff[i] = run; run += wtot[i]; ft += wsumf[i]; }
        ftot_s = ft;
        loss[0] = 0.f;
    }
    __syncthreads();
    float ntot = ftot_s;
    cs[t] = (cls + EPS_) / (ntot + KCENT * EPS_) * ntot;
    int excl = woff[w] + inc - c;
    start[t] = excl;
    cursor16[t * 16] = excl;
}

// ---------- K4: scatter with block-aggregated ranks ----------
__global__ __launch_bounds__(256) void k_scatter(
    const int* __restrict__ ind, int* __restrict__ cursor16,
    int2* __restrict__ pk) {
    __shared__ int lh[KCENT];
#pragma unroll
    for (int i = 0; i < KCENT / 256; ++i) lh[threadIdx.x + i * 256] = 0;
    __syncthreads();

    const int n  = blockIdx.x * 256 + threadIdx.x;
    const int bi = ind[n];
    const int rank = atomicAdd(&lh[bi], 1);
    __syncthreads();

#pragma unroll
    for (int i = 0; i < KCENT / 256; ++i) {
        int k = threadIdx.x + i * 256;
        int c = lh[k];
        int base = 0;
        if (c) base = atomicAdd(&cursor16[k * 16], c);
        lh[k] = base;
    }
    __syncthreads();

    pk[lh[bi] + rank] = make_int2(n, bi);
}

// ---------- K5: segment sum over uniform 32-row wave-windows ----------
__global__ __launch_bounds__(256) void k_segsum(
    const float* __restrict__ x, const int2* __restrict__ pk,
    float* __restrict__ csum) {
    const int wgid = blockIdx.x * 4 + (threadIdx.x >> 6);  // 0..4095
    const int lane = threadIdx.x & 63;
    const int r0   = wgid * 32;

    float acc = 0.f;
    int cur = pk[r0].y;
#pragma unroll 4
    for (int r = r0; r < r0 + 32; r += 2) {
        int2 a = pk[r];
        int2 b = pk[r + 1];
        float v0 = x[(size_t)a.x * DIM + lane];
        float v1 = x[(size_t)b.x * DIM + lane];
        if (a.y != cur) {
            atomicAdd(&csum[(size_t)cur * DIM + lane], acc);
            acc = 0.f; cur = a.y;
        }
        acc += v0;
        if (b.y != cur) {
            atomicAdd(&csum[(size_t)cur * DIM + lane], acc);
            acc = 0.f; cur = b.y;
        }
        acc += v1;
    }
    atomicAdd(&csum[(size_t)cur * DIM + lane], acc);
}

// ---------- K6: centroids_new, stored transposed [K][D] ----------
__global__ void k_newcent(const float* __restrict__ avg,
                          const float* __restrict__ csum,
                          const float* __restrict__ cs,
                          float* __restrict__ cnewT) {
    int idx = blockIdx.x * blockDim.x + threadIdx.x;  // = k*64 + d
    int k = idx >> 6, d = idx & 63;
    float v = DECAY * avg[d * KCENT + k] + (1.0f - DECAY) * csum[idx];
    cnewT[idx] = v / cs[k];
}

// ---------- K7: gather quantized rows + MSE loss ----------
__global__ __launch_bounds__(256) void k_out(
    const float* __restrict__ x, const int* __restrict__ ind,
    const float* __restrict__ cnewT, float* __restrict__ out,
    float* __restrict__ loss) {
    const int tid = threadIdx.x;
    const int l16 = tid & 15;
    float p = 0.f;

    for (int g = blockIdx.x; g < NROWS / 16; g += 2048) {
        int row = g * 16 + (tid >> 4);
        int k = ind[row];
        float4 q  = ((const float4*)(cnewT + (size_t)k * DIM))[l16];
        float4 xw = ((const float4*)(x + (size_t)row * DIM))[l16];
        ((float4*)(out + (size_t)row * DIM))[l16] = q;
        float dx = xw.x - q.x, dy = xw.y - q.y, dz = xw.z - q.z, dw = xw.w - q.w;
        p += dx * dx + dy * dy + dz * dz + dw * dw;
    }

    __shared__ float red[256];
    red[tid] = p;
    __syncthreads();
    for (int off = 128; off > 0; off >>= 1) {
        if (tid < off) red[tid] += red[tid + off];
        __syncthreads();
    }
    if (tid == 0)
        atomicAdd(loss, red[0] * (1.0f / ((float)NROWS * (float)DIM)));
}

extern "C" void kernel_launch(void* const* d_in, const int* in_sizes, int n_in,
                              void* d_out, int out_size, void* d_ws, size_t ws_size,
                              hipStream_t stream) {
    const float* x            = (const float*)d_in[0];
    const float* cent         = (const float*)d_in[1];
    const float* cluster_size = (const float*)d_in[2];
    const float* avg          = (const float*)d_in[3];
    float* out = (float*)d_out;

    float* ws       = (float*)d_ws;
    float* csum     = ws;                     // K*D
    int*   cnt      = (int*)(ws + 65536);     // K
    float* cs       = ws + 66560;             // K
    float* cnewT    = ws + 67584;             // K*D
    int*   ind      = (int*)(ws + 133120);    // N
    int2*  pk       = (int2*)(ws + 264192);   // N int2
    int*   start    = (int*)(ws + 526336);    // K
    int*   cursor16 = (int*)(ws + 527360);    // 16K
    u32*   centB    = (u32*)(ws + 543744);    // 66560 u32 frag-major
    float* loss     = out + (size_t)NROWS * DIM;

    k_ctrans <<<KCENT / 256, 256, 0, stream>>>(cent, centB, csum);
    k_assign <<<NROWS / 256, 256, 0, stream>>>(x, centB, ind, cnt);
    k_scan   <<<1, KCENT, 0, stream>>>(cluster_size, cnt, cs, start, cursor16, loss);
    k_scatter<<<NROWS / 256, 256, 0, stream>>>(ind, cursor16, pk);
    k_segsum <<<NROWS / 128, 256, 0, stream>>>(x, pk, csum);
    k_newcent<<<(KCENT * DIM) / 256, 256, 0, stream>>>(avg, csum, cs, cnewT);
    k_out    <<<2048, 256, 0, stream>>>(x, ind, cnewT, out, loss);
}

// Round 6
// 186.379 us; speedup vs baseline: 1.1847x; 1.1749x over previous
//
#include <hip/hip_runtime.h>
#include <math.h>

#define NROWS 131072
#define DIM   64
#define KCENT 1024
#define DECAY 0.99f
#define EPS_  1e-5f
#define INV_ND (1.0f / ((float)NROWS * (float)DIM))

typedef unsigned int u32;
typedef unsigned short u16;
typedef __attribute__((ext_vector_type(8))) short short8b;
typedef __attribute__((ext_vector_type(16))) float floatx16;

// ---------------- ws layout (float elements) ----------------
// csum    [K*D]    @ 0        (zeroed by k_ctrans)
// cnt     [K]      @ 65536    (int, zeroed by k_ctrans)
// cs      [K]      @ 66560
// cnewT   [K*D]    @ 67584
// ind     [N]      @ 133120   (int)
// pk      [N]      @ 264192   (int2: {row, cluster} in sorted order)
// xsqp    [512]    @ 526336   (float; per-block sum(x^2) partials — reuses the
//                              old `start` slot, which nothing consumed)
// cursor16[K*16]   @ 527360   (int, 64B-spread atomic cursors)
// centB   [K*68]   @ 543744   (u32: bf16 hi 32dw | lo 32dw | csq@64 | pad; 272B rows)
//
// loss refactor: mean((x-q)^2) = [ Sum x^2  - 2 Sum_k <cnewT_k, csum_k>
//                                  + Sum_k cnt_k*||cnewT_k||^2 ] / (N*D)
//   Sum x^2            -> k_assign (x already in regs) -> xsqp -> k_scan
//   cross + quad terms -> k_newcent (already touches every cnewT/csum elem)
//   => k_out never reads x: pure gather-store.

__device__ inline u16 bf16rne(float f) {
    u32 u = __float_as_uint(f);
    return (u16)((u + 0x7FFFu + ((u >> 16) & 1u)) >> 16);
}

// ---------- K1: centroid transpose/split + zero csum/cnt ----------
__global__ void k_ctrans(const float* __restrict__ cent, u32* __restrict__ centB,
                         float* __restrict__ zero_base) {
    int tid = blockIdx.x * 256 + threadIdx.x;   // 0..1023
    // zero csum+cnt (66560 floats = 16640 float4)
    float4 z = make_float4(0.f, 0.f, 0.f, 0.f);
    for (int i = tid; i < 16640; i += 1024) ((float4*)zero_base)[i] = z;

    int k = tid;
    u32* row = centB + (size_t)k * 68;
    float csq = 0.f;
#pragma unroll
    for (int d0 = 0; d0 < 32; ++d0) {
        float f0 = cent[(2 * d0) * KCENT + k];      // coalesced across lanes
        float f1 = cent[(2 * d0 + 1) * KCENT + k];
        u16 h0 = bf16rne(f0), h1 = bf16rne(f1);
        u16 s0 = bf16rne(f0 - __uint_as_float((u32)h0 << 16));
        u16 s1 = bf16rne(f1 - __uint_as_float((u32)h1 << 16));
        csq = fmaf(f0, f0, fmaf(f1, f1, csq));
        row[d0]      = (u32)h0 | ((u32)h1 << 16);   // hi
        row[32 + d0] = (u32)s0 | ((u32)s1 << 16);   // lo
    }
    row[64] = __float_as_uint(csq);
}

// ---------- K2: MFMA assignment (R1 structure — best measured, 62us) ----------
// dot ~= xh.ch + xh.cl + xl.ch ; C layout (m74/m101): col=lane&31,
// row=(reg&3)+8*(reg>>2)+4*(lane>>5).
// 512 thr (8 waves x 32 rows), 16 waves/CU; global_load_lds staging, one
// barrier pair per tile; acc init -0.5||c||^2, tag-packed argmax epilogue.
// v7 addition: free Sum x^2 (from f32 values pre-bf16-conversion).
__global__ __launch_bounds__(512, 4) void k_assign(
    const float* __restrict__ x, const u32* __restrict__ centB,
    int* __restrict__ ind, int* __restrict__ cnt, float* __restrict__ xsqp) {
    __shared__ __align__(16) char buf[2][17408];   // 64 cents x 272B, double-buffered
    __shared__ int hist[KCENT];
    __shared__ float xsq_lds;
    const int tid  = threadIdx.x;                  // 0..511
    const int lane = tid & 63;
    const int wid  = tid >> 6;                     // 0..7
    const int half = lane >> 5;
    const int nl   = lane & 31;

    hist[tid] = 0;
    hist[tid + 512] = 0;
    if (tid == 0) xsq_lds = 0.f;

    const int rowbase = blockIdx.x * 256 + wid * 32;

    // A-frags: 4 hi + 4 lo for this wave's 32 rows (dims t4*16+half*8 .. +8)
    short8b ah[4], al[4];
    float xsq = 0.f;
    {
        const float* xr = x + (size_t)(rowbase + nl) * DIM;
#pragma unroll
        for (int t4 = 0; t4 < 4; ++t4) {
            int d0 = t4 * 16 + half * 8;
            float4 f0 = *(const float4*)(xr + d0);
            float4 f1 = *(const float4*)(xr + d0 + 4);
            float fv[8] = {f0.x, f0.y, f0.z, f0.w, f1.x, f1.y, f1.z, f1.w};
            short8b va, vb;
#pragma unroll
            for (int j = 0; j < 8; ++j) {
                xsq = fmaf(fv[j], fv[j], xsq);
                u16 h = bf16rne(fv[j]);
                float lo = fv[j] - __uint_as_float((u32)h << 16);
                va[j] = (short)h;
                vb[j] = (short)bf16rne(lo);
            }
            ah[t4] = va;
            al[t4] = vb;
        }
    }
    // wave-reduce Sum x^2 (covers all 64 dims of this wave's 32 rows)
#pragma unroll
    for (int m = 1; m < 64; m <<= 1) xsq += __shfl_xor(xsq, m, 64);

    float best[16];
#pragma unroll
    for (int r = 0; r < 16; ++r) best[r] = __uint_as_float(0xFF800000u); // -inf

    // staging: tile kt = 17408B = 17 granule-blocks of 1KB; block b -> wave (b%8)
    const char* gbase = (const char*)centB;
#define STAGE(KT, DST)                                                              \
    {                                                                               \
        const char* _src = gbase + (size_t)(KT) * 17408;                            \
        for (int b = wid; b < 17; b += 8) {                                         \
            __builtin_amdgcn_global_load_lds(                                       \
                (const __attribute__((address_space(1))) u32*)(_src + b * 1024 +    \
                                                               lane * 16),          \
                (__attribute__((address_space(3))) u32*)((DST) + b * 1024),         \
                16, 0, 0);                                                          \
        }                                                                           \
    }

    STAGE(0, buf[0]);
    __syncthreads();   // drains vmcnt(0): tile 0 landed; xsq_lds init visible
    if (lane == 0) atomicAdd(&xsq_lds, xsq);

    for (int kt = 0; kt < 16; ++kt) {
        char* b = buf[kt & 1];
        if (kt < 15) STAGE(kt + 1, buf[(kt + 1) & 1]);  // drained at closing barrier

#pragma unroll
        for (int sub = 0; sub < 2; ++sub) {
            const char* base = b + (size_t)(sub * 32 + nl) * 272 + half * 16;
            short8b bh[4], bl[4];
#pragma unroll
            for (int t4 = 0; t4 < 4; ++t4) bh[t4] = *(const short8b*)(base + t4 * 32);
#pragma unroll
            for (int t4 = 0; t4 < 4; ++t4) bl[t4] = *(const short8b*)(base + 128 + t4 * 32);
            float cq = *(const float*)(b + (size_t)(sub * 32 + nl) * 272 + 256);
            float mh = -0.5f * cq;

            floatx16 acc;
#pragma unroll
            for (int i = 0; i < 16; ++i) acc[i] = mh;
#pragma unroll
            for (int t4 = 0; t4 < 4; ++t4)
                acc = __builtin_amdgcn_mfma_f32_32x32x16_bf16(ah[t4], bh[t4], acc, 0, 0, 0);
#pragma unroll
            for (int t4 = 0; t4 < 4; ++t4)
                acc = __builtin_amdgcn_mfma_f32_32x32x16_bf16(ah[t4], bl[t4], acc, 0, 0, 0);
#pragma unroll
            for (int t4 = 0; t4 < 4; ++t4)
                acc = __builtin_amdgcn_mfma_f32_32x32x16_bf16(al[t4], bh[t4], acc, 0, 0, 0);

            const u32 tag = (u32)(kt * 2 + sub);     // 5 bits; cidx = tag*32 + nl
#pragma unroll
            for (int r = 0; r < 16; ++r) {
                u32 pkv = (__float_as_uint(acc[r]) & 0xFFFFFFE0u) | tag;
                best[r] = fmaxf(best[r], __uint_as_float(pkv));
            }
        }
        __syncthreads();   // tile kt+1 landed; buf[kt&1] reusable
    }
#undef STAGE

    // cross-lane argmax within each 32-lane half; unpack 5-bit tag + lane -> cidx
#pragma unroll
    for (int r = 0; r < 16; ++r) {
        float b0 = best[r];
        int   i0 = ((int)(__float_as_uint(b0) & 31u) << 5) | nl;
#pragma unroll
        for (int m = 1; m < 32; m <<= 1) {
            float bp = __shfl_xor(b0, m, 64);
            int   ip = __shfl_xor(i0, m, 64);
            if (bp > b0 || (bp == b0 && ip < i0)) { b0 = bp; i0 = ip; }
        }
        if (nl == 0) {
            int mrow = (r & 3) + 8 * (r >> 2) + 4 * half;
            ind[rowbase + mrow] = i0;
            atomicAdd(&hist[i0], 1);
        }
    }
    __syncthreads();
    {
        int v0 = hist[tid];
        if (v0) atomicAdd(&cnt[tid], v0);
        int v1 = hist[tid + 512];
        if (v1) atomicAdd(&cnt[tid + 512], v1);
    }
    if (tid == 0) xsqp[blockIdx.x] = xsq_lds;
}

// ---------- K3: EMA stats + Laplace cs + prefix sum + loss x^2-term ----------
__global__ void k_scan(const float* __restrict__ cluster_size,
                       const int* __restrict__ cnt,
                       float* __restrict__ cs,
                       int* __restrict__ cursor16,
                       const float* __restrict__ xsqp,
                       float* __restrict__ loss) {
    __shared__ float wsumf[16];
    __shared__ int   wtot[16];
    __shared__ int   woff[16];
    __shared__ float xs[8];
    __shared__ float ftot_s;
    const int t = threadIdx.x;           // 0..1023
    const int lane = t & 63, w = t >> 6;
    const int c = cnt[t];
    float cls = DECAY * cluster_size[t] + (1.0f - DECAY) * (float)c;

    // Sum x^2 partials (512 of them) reduced by waves 0..7
    if (t < 512) {
        float v = xsqp[t];
#pragma unroll
        for (int m = 1; m < 64; m <<= 1) v += __shfl_xor(v, m, 64);
        if (lane == 0) xs[w] = v;
    }

    // wave reduce (float) + wave inclusive scan (int)
    float s = cls;
#pragma unroll
    for (int m = 1; m < 64; m <<= 1) s += __shfl_xor(s, m, 64);
    int inc = c;
#pragma unroll
    for (int m = 1; m < 64; m <<= 1) {
        int u = __shfl_up(inc, m, 64);
        if (lane >= m) inc += u;
    }
    if (lane == 0)  wsumf[w] = s;
    if (lane == 63) wtot[w]  = inc;
    __syncthreads();
    if (t == 0) {
        int run = 0; float ft = 0.f;
#pragma unroll
        for (int i = 0; i < 16; ++i) { woff[i] = run; run += wtot[i]; ft += wsumf[i]; }
        ftot_s = ft;
        float xt = 0.f;
#pragma unroll
        for (int i = 0; i < 8; ++i) xt += xs[i];
        loss[0] = xt * INV_ND;          // Sum x^2 term; k_newcent adds the rest
    }
    __syncthreads();
    float ntot = ftot_s;
    cs[t] = (cls + EPS_) / (ntot + KCENT * EPS_) * ntot;
    int excl = woff[w] + inc - c;
    cursor16[t * 16] = excl;
}

// ---------- K4: scatter with block-aggregated ranks ----------
__global__ __launch_bounds__(256) void k_scatter(
    const int* __restrict__ ind, int* __restrict__ cursor16,
    int2* __restrict__ pk) {
    __shared__ int lh[KCENT];
#pragma unroll
    for (int i = 0; i < KCENT / 256; ++i) lh[threadIdx.x + i * 256] = 0;
    __syncthreads();

    const int n  = blockIdx.x * 256 + threadIdx.x;
    const int bi = ind[n];
    const int rank = atomicAdd(&lh[bi], 1);   // LDS atomic: old = my rank
    __syncthreads();

#pragma unroll
    for (int i = 0; i < KCENT / 256; ++i) {
        int k = threadIdx.x + i * 256;
        int c = lh[k];
        int base = 0;
        if (c) base = atomicAdd(&cursor16[k * 16], c);  // one per distinct cluster
        lh[k] = base;
    }
    __syncthreads();

    pk[lh[bi] + rank] = make_int2(n, bi);
}

// ---------- K5: segment sum over uniform 32-row wave-windows ----------
__global__ __launch_bounds__(256) void k_segsum(
    const float* __restrict__ x, const int2* __restrict__ pk,
    float* __restrict__ csum) {
    const int wgid = blockIdx.x * 4 + (threadIdx.x >> 6);  // 0..4095
    const int lane = threadIdx.x & 63;
    const int r0   = wgid * 32;

    float acc = 0.f;
    int cur = pk[r0].y;
#pragma unroll 4
    for (int r = r0; r < r0 + 32; r += 2) {
        int2 a = pk[r];                   // wave-uniform -> scalar 8B load
        int2 b = pk[r + 1];
        float v0 = x[(size_t)a.x * DIM + lane];   // coalesced 256B/row
        float v1 = x[(size_t)b.x * DIM + lane];
        if (a.y != cur) {                 // wave-uniform branch, rare
            atomicAdd(&csum[(size_t)cur * DIM + lane], acc);
            acc = 0.f; cur = a.y;
        }
        acc += v0;
        if (b.y != cur) {
            atomicAdd(&csum[(size_t)cur * DIM + lane], acc);
            acc = 0.f; cur = b.y;
        }
        acc += v1;
    }
    atomicAdd(&csum[(size_t)cur * DIM + lane], acc);
}

// ---------- K6: centroids_new [K][D] + loss cross/quad terms ----------
__global__ __launch_bounds__(256) void k_newcent(
    const float* __restrict__ avg, const float* __restrict__ csum,
    const float* __restrict__ cs, const int* __restrict__ cnt,
    float* __restrict__ cnewT, float* __restrict__ loss) {
    int idx = blockIdx.x * 256 + threadIdx.x;         // = k*64 + d
    int k = idx >> 6, d = idx & 63;
    float cv = csum[idx];
    float v = DECAY * avg[d * KCENT + k] + (1.0f - DECAY) * cv;
    v = v / cs[k];
    cnewT[idx] = v;
    // loss terms: cnt_k * v^2 - 2 * v * csum  (summed over all [k][d])
    float p = v * (fmaf((float)cnt[k], v, -2.0f * cv));

    __shared__ float red[256];
    red[threadIdx.x] = p;
    __syncthreads();
    for (int off = 128; off > 0; off >>= 1) {
        if (threadIdx.x < off) red[threadIdx.x] += red[threadIdx.x + off];
        __syncthreads();
    }
    if (threadIdx.x == 0) atomicAdd(loss, red[0] * INV_ND);
}

// ---------- K7: pure gather-store (no x read, no loss) ----------
__global__ __launch_bounds__(256) void k_out(
    const int* __restrict__ ind, const float* __restrict__ cnewT,
    float* __restrict__ out) {
    const int tid = threadIdx.x;
    const int l16 = tid & 15;
#pragma unroll
    for (int it = 0; it < 4; ++it) {
        int g = blockIdx.x + it * 2048;               // 8192 groups of 16 rows
        int row = g * 16 + (tid >> 4);
        int k = ind[row];
        float4 q = ((const float4*)(cnewT + (size_t)k * DIM))[l16];
        ((float4*)(out + (size_t)row * DIM))[l16] = q;
    }
}

extern "C" void kernel_launch(void* const* d_in, const int* in_sizes, int n_in,
                              void* d_out, int out_size, void* d_ws, size_t ws_size,
                              hipStream_t stream) {
    const float* x            = (const float*)d_in[0];
    const float* cent         = (const float*)d_in[1];
    const float* cluster_size = (const float*)d_in[2];
    const float* avg          = (const float*)d_in[3];
    float* out = (float*)d_out;

    float* ws       = (float*)d_ws;
    float* csum     = ws;                     // K*D
    int*   cnt      = (int*)(ws + 65536);     // K
    float* cs       = ws + 66560;             // K
    float* cnewT    = ws + 67584;             // K*D
    int*   ind      = (int*)(ws + 133120);    // N
    int2*  pk       = (int2*)(ws + 264192);   // N int2
    float* xsqp     = ws + 526336;            // 512 (old `start` slot)
    int*   cursor16 = (int*)(ws + 527360);    // 16K
    u32*   centB    = (u32*)(ws + 543744);    // K*68
    float* loss     = out + (size_t)NROWS * DIM;

    k_ctrans <<<KCENT / 256, 256, 0, stream>>>(cent, centB, csum);
    k_assign <<<NROWS / 256, 512, 0, stream>>>(x, centB, ind, cnt, xsqp);
    k_scan   <<<1, KCENT, 0, stream>>>(cluster_size, cnt, cs, cursor16, xsqp, loss);
    k_scatter<<<NROWS / 256, 256, 0, stream>>>(ind, cursor16, pk);
    k_segsum <<<NROWS / 128, 256, 0, stream>>>(x, pk, csum);
    k_newcent<<<(KCENT * DIM) / 256, 256, 0, stream>>>(avg, csum, cs, cnt, cnewT, loss);
    k_out    <<<2048, 256, 0, stream>>>(ind, cnewT, out);
}